// Round 2
// baseline (16296.233 us; speedup 1.0000x reference)
//
#include <hip/hip_runtime.h>

// LSTM: S=4096, I=64, H=1024, O=1, fp32.
// Persistent cooperative kernel, 128 blocks x 512 threads.
// Round-11: BARRIER-FREE WAVE DATAFLOW.
//   r1 post-mortem: inbox fan-out regressed (reader contention was NOT the
//   bottleneck). Remaining per-step overhead is protocol coupling:
//   __syncthreads (max-of-16-pollers skew, ~RT/2) + wave0 relay publish hop
//   (~300 cyc serial before the store leaves the CU).
//   This round removes BOTH:
//   - transposed GEMV layout: lane l holds W[q][64c+l] for q=0..3,c=0..15
//     (same 68 weight VGPRs), computes partials for ALL 4 gates; 6-shuffle
//     reduce-scatter (groups of 16 lanes = gates i,f,g,o) replaces old reduce.
//   - wave w polls ONLY its own 2 global chunk-slots (tag s), relays them to
//     a tagged LDS buffer; consumes the other 14 chunks via cheap LDS
//     tag-polls (ds RT ~40-120cy vs ~900 global), issued 16-deep (lgkmcnt
//     pipelines in order).
//   - producer lane0 stores its tagged 8B {tag:32|h:32} DIRECTLY to global.
//   - no __syncthreads in the step loop at all; waves run decoupled.
//   Safety (induction, per wave): publish(tag s+1) happens only after
//   consume-all(tag s); a tag s+2 write (same parity slot) can only occur
//   after every wave consumed tag s. LDS relay slots carry the same tags,
//   pre-initialized to 0xFFFFFFFF (never a valid tag). No fences needed:
//   tag+data share one 64-bit atom.
// Weights stay LDS-sourced -> named registers (NOT remat-able, round-9).

#define SEQ_LEN 4096
#define HID 1024
#define NBLK 128
#define TPB 512
#define HPB 8      // h-indices per block (one per wave)

#define ALD(p)    __hip_atomic_load((p), __ATOMIC_RELAXED, __HIP_MEMORY_SCOPE_AGENT)
#define AST(p,v)  __hip_atomic_store((p), (v), __ATOMIC_RELAXED, __HIP_MEMORY_SCOPE_AGENT)
#define LLD(p)    __hip_atomic_load((p), __ATOMIC_RELAXED, __HIP_MEMORY_SCOPE_WORKGROUP)
#define LST(p,v)  __hip_atomic_store((p), (v), __ATOMIC_RELAXED, __HIP_MEMORY_SCOPE_WORKGROUP)

__device__ __forceinline__ float fast_sigmoid(float x) {
    return __builtin_amdgcn_rcpf(1.0f + __builtin_amdgcn_exp2f(-1.4426950408889634f * x));
}
__device__ __forceinline__ float fast_tanh(float x) {
    return fmaf(-2.0f, __builtin_amdgcn_rcpf(1.0f + __builtin_amdgcn_exp2f(2.8853900817779268f * x)), 1.0f);
}

// ws: unsigned long long slots[2][1024]. {tag:32 | fp32 bits:32}. Zero-init:
// buffer0 tag0/val0 == h_0 = 0 (correct); buffer1 receives odd tags.
__global__ void lstm_init_kernel(unsigned long long* ws) {
    int t = blockIdx.x * blockDim.x + threadIdx.x;
    if (t < 2048) ws[t] = 0ull;
}

__global__ __launch_bounds__(TPB, 1) void lstm_persistent_kernel(
    const float* __restrict__ input,   // [4096][64]
    const float* __restrict__ W_ih,    // [4096][64]
    const float* __restrict__ W_hh,    // [4096][1024]
    const float* __restrict__ b_ih,    // [4096]
    const float* __restrict__ b_hh,    // [4096]
    const float* __restrict__ W_lin,   // [1][1024]
    const float* __restrict__ b_lin,   // [1]
    float* __restrict__ out,           // [1]
    unsigned long long* __restrict__ ws)
{
    const int t = threadIdx.x;
    const int b = blockIdx.x;
    const int w = t >> 6;      // wave in block (0..7)
    const int l = t & 63;      // lane
    const int j = HPB * b + w; // owned h index

    __shared__ float wlds[32 * 1024];            // 128 KB: block's 32 W_hh rows
    __shared__ float wih[32 * 64];               // 8 KB: block's 32 W_ih rows
    __shared__ unsigned long long hls[2 * HID];  // 16 KB tagged LDS relay
    __shared__ float red[HPB];

    // ---- stage W_hh rows: LDS row r=q*8+w <- global row q*1024+8b+w ----
    {
        float4* wl4 = (float4*)wlds;
        #pragma unroll
        for (int i = 0; i < 16; ++i) {
            int flat = i * TPB + t;          // 0..8191
            int rr = flat >> 8;              // LDS row 0..31
            int cc = flat & 255;             // float4 col
            int row_g = ((rr >> 3) << 10) + HPB * b + (rr & 7);
            wl4[flat] = ((const float4*)(W_hh + (size_t)row_g * HID))[cc];
        }
    }
    // ---- stage W_ih rows (32 x 64 floats = 512 float4, one per thread) ----
    {
        float4* wi4 = (float4*)wih;
        int rr = t >> 4, cc = t & 15;
        int row_g = ((rr >> 3) << 10) + HPB * b + (rr & 7);
        wi4[t] = ((const float4*)(W_ih + (size_t)row_g * 64))[cc];
    }
    float bias[4];
    #pragma unroll
    for (int q = 0; q < 4; ++q) bias[q] = b_ih[(q << 10) + j] + b_hh[(q << 10) + j];
    // ---- init LDS relay tags to invalid (0xFFFFFFFF never a valid tag) ----
    #pragma unroll
    for (int k = 0; k < 4; ++k) hls[t + TPB * k] = 0xFFFFFFFF00000000ull;
    __syncthreads();   // one-time: weights staged + relay initialized

    // ---- LDS -> named registers (not remat-able; RA keeps in VGPRs) ----
    // W##q##_c = W_hh[q*1024 + j][64c + l]
#define DECLW(q) \
    const float* wb##q = wlds + ((((q) << 3) | w) << 10) + l;                              \
    const float W##q##_0 = wb##q[0],    W##q##_1 = wb##q[64],   W##q##_2 = wb##q[128],     \
                W##q##_3 = wb##q[192],  W##q##_4 = wb##q[256],  W##q##_5 = wb##q[320],     \
                W##q##_6 = wb##q[384],  W##q##_7 = wb##q[448],  W##q##_8 = wb##q[512],     \
                W##q##_9 = wb##q[576],  W##q##_10 = wb##q[640], W##q##_11 = wb##q[704],    \
                W##q##_12 = wb##q[768], W##q##_13 = wb##q[832], W##q##_14 = wb##q[896],    \
                W##q##_15 = wb##q[960];
    DECLW(0) DECLW(1) DECLW(2) DECLW(3)
#undef DECLW
    const float Wih0 = wih[((0 << 3) | w) * 64 + l];
    const float Wih1 = wih[((1 << 3) | w) * 64 + l];
    const float Wih2 = wih[((2 << 3) | w) * 64 + l];
    const float Wih3 = wih[((3 << 3) | w) * 64 + l];

    float c_state = 0.0f;

    for (int s = 0; s < SEQ_LEN; ++s) {
        const int par = s & 1;
        unsigned long long* rs = ws + (par << 10);
        unsigned long long* hl = hls + (par << 10);
        const unsigned tag = (unsigned)s;

        float xv = input[(s << 6) + l];   // issue early; cacheable

        // ---- poll our own 2 global chunk-slots (wave-private, coalesced) ----
        unsigned long long v0, v1;
        bool r0 = false, r1 = false;
        do {
            if (!r0) { v0 = ALD(&rs[(w << 7) + l]);      r0 = ((unsigned)(v0 >> 32) == tag); }
            if (!r1) { v1 = ALD(&rs[(w << 7) + 64 + l]); r1 = ((unsigned)(v1 >> 32) == tag); }
        } while (!(r0 && r1));

        // ---- relay to tagged LDS (same-atom tag+data; no fence needed) ----
        LST(&hl[(w << 7) + l],      v0);
        LST(&hl[(w << 7) + 64 + l], v1);

        // ---- issue all 16 chunk reads (in-order ds returns pipeline them) ----
#define UINIT(c) unsigned long long u##c = LLD(&hl[((c) << 6) + l]);
        UINIT(0)  UINIT(1)  UINIT(2)  UINIT(3)
        UINIT(4)  UINIT(5)  UINIT(6)  UINIT(7)
        UINIT(8)  UINIT(9)  UINIT(10) UINIT(11)
        UINIT(12) UINIT(13) UINIT(14) UINIT(15)
#undef UINIT

        float a0 = 0.f, a1 = 0.f, a2 = 0.f, a3 = 0.f;
#define CHUNK(c) {                                                                         \
        while (!__all((int)((unsigned)(u##c >> 32) == tag)))                               \
            u##c = LLD(&hl[((c) << 6) + l]);                                               \
        const float hv = __uint_as_float((unsigned)(u##c & 0xffffffffull));                \
        a0 = fmaf(W0_##c, hv, a0); a1 = fmaf(W1_##c, hv, a1);                              \
        a2 = fmaf(W2_##c, hv, a2); a3 = fmaf(W3_##c, hv, a3); }
        CHUNK(0)  CHUNK(1)  CHUNK(2)  CHUNK(3)
        CHUNK(4)  CHUNK(5)  CHUNK(6)  CHUNK(7)
        CHUNK(8)  CHUNK(9)  CHUNK(10) CHUNK(11)
        CHUNK(12) CHUNK(13) CHUNK(14) CHUNK(15)
#undef CHUNK
        a0 = fmaf(Wih0, xv, a0); a1 = fmaf(Wih1, xv, a1);
        a2 = fmaf(Wih2, xv, a2); a3 = fmaf(Wih3, xv, a3);

        // ---- reduce-scatter: gate q's sum lands on lane group q*16..q*16+15 ----
        float x_, y_;
        x_ = (l & 16) ? a0 : a1;  y_ = (l & 16) ? a1 : a0;
        float s01 = y_ + __shfl_xor(x_, 16);
        x_ = (l & 16) ? a2 : a3;  y_ = (l & 16) ? a3 : a2;
        float s23 = y_ + __shfl_xor(x_, 16);
        x_ = (l & 32) ? s01 : s23; y_ = (l & 32) ? s23 : s01;
        float acc = y_ + __shfl_xor(x_, 32);
        acc += __shfl_xor(acc, 1);
        acc += __shfl_xor(acc, 2);
        acc += __shfl_xor(acc, 4);
        acc += __shfl_xor(acc, 8);

        float gi = __shfl(acc, 0)  + bias[0];
        float gf = __shfl(acc, 16) + bias[1];
        float gg = __shfl(acc, 32) + bias[2];
        float go = __shfl(acc, 48) + bias[3];

        float ig = fast_sigmoid(gi);
        float fg = fast_sigmoid(gf);
        float cg = fast_tanh(gg);
        float og = fast_sigmoid(go);
        c_state  = fmaf(fg, c_state, ig * cg);
        float hn = og * fast_tanh(c_state);

        // ---- publish: tagged 8B straight to global (no relay hop) ----
        if (l == 0) {
            unsigned long long pv = ((unsigned long long)(unsigned)(s + 1) << 32) |
                                    (unsigned long long)__float_as_uint(hn);
            AST(&ws[(((s + 1) & 1) << 10) + j], pv);
        }
    }

    // ---- final projection: h_4096 (tag 4096, even -> buffer 0) ----
    if (b == 0) {
        const unsigned tag = (unsigned)SEQ_LEN;
        unsigned long long v0, v1;
        bool r0 = false, r1 = false;
        do {
            if (!r0) { v0 = ALD(&ws[t      ]); r0 = ((unsigned)(v0 >> 32) == tag); }
            if (!r1) { v1 = ALD(&ws[t + 512]); r1 = ((unsigned)(v1 >> 32) == tag); }
        } while (!(r0 && r1));
        float p = __uint_as_float((unsigned)(v0 & 0xffffffffull)) * W_lin[t] +
                  __uint_as_float((unsigned)(v1 & 0xffffffffull)) * W_lin[t + 512];
        #pragma unroll
        for (int m = 32; m >= 1; m >>= 1) p += __shfl_xor(p, m);
        if (l == 0) red[w] = p;
        __syncthreads();
        if (t == 0) {
            float r = 0.f;
            #pragma unroll
            for (int k = 0; k < HPB; ++k) r += red[k];
            out[0] = r + b_lin[0];
        }
    }
}

extern "C" void kernel_launch(void* const* d_in, const int* in_sizes, int n_in,
                              void* d_out, int out_size, void* d_ws, size_t ws_size,
                              hipStream_t stream) {
    const float* input = (const float*)d_in[0];
    const float* W_ih  = (const float*)d_in[1];
    const float* W_hh  = (const float*)d_in[2];
    const float* b_ih  = (const float*)d_in[3];
    const float* b_hh  = (const float*)d_in[4];
    const float* W_lin = (const float*)d_in[5];
    const float* b_lin = (const float*)d_in[6];
    float* out = (float*)d_out;
    unsigned long long* ws = (unsigned long long*)d_ws;

    hipLaunchKernelGGL(lstm_init_kernel, dim3(8), dim3(256), 0, stream, ws);

    void* args[] = { (void*)&input, (void*)&W_ih, (void*)&W_hh, (void*)&b_ih,
                     (void*)&b_hh, (void*)&W_lin, (void*)&b_lin, (void*)&out, (void*)&ws };
    (void)hipLaunchCooperativeKernel((void*)lstm_persistent_kernel, dim3(NBLK), dim3(TPB),
                                     args, 0, stream);
}

// Round 3
// 9111.884 us; speedup vs baseline: 1.7885x; 1.7885x over previous
//
#include <hip/hip_runtime.h>

// LSTM: S=4096, I=64, H=1024, O=1, fp32.
// Persistent cooperative kernel, 128 blocks x 512 threads (r6 skeleton).
// Round-9: weights in REGISTERS (LDS-sourced reads are not remat-able).
// Round-10 (inbox fan-out) REGRESSED: reader contention is not the bottleneck.
// Round-11 (barrier-free wave dataflow) REGRESSED 2x: per-wave 8B publishes
//   fragmented the 64B publish line (WRITE_SIZE 4x, slow visibility) and the
//   relay added a serial hop. r0 skeleton restored exactly.
// Round-12 change (this round): DEPTH-2 ROTATED POLLING only.
//   Theory: with one poll load in flight per address, sampling period = MALL
//   RT; detection jitter is a full RT and the barrier pays max-of-16 of it
//   (~1.9 RT). Keeping two batches in flight (check batch A while batch B
//   flies -> s_waitcnt vmcnt(2)) halves the sampling period: detection
//   ~1.25 RT mean / ~1.5 RT max. Everything else byte-identical to r0:
//   tagged 8-byte atoms {tag:32|h:32}, relaxed agent atomics, tagged double
//   buffer, zero fences, one __syncthreads per step, wave-0 gather +
//   coalesced 64B line publish (WRITE_SIZE must stay 32768 KB).

#define SEQ_LEN 4096
#define HID 1024
#define NBLK 128
#define TPB 512
#define HPB 8      // h-indices per block (one per wave)

#define ALD(p)    __hip_atomic_load((p), __ATOMIC_RELAXED, __HIP_MEMORY_SCOPE_AGENT)
#define AST(p,v)  __hip_atomic_store((p), (v), __ATOMIC_RELAXED, __HIP_MEMORY_SCOPE_AGENT)

__device__ __forceinline__ float fast_sigmoid(float x) {
    return __builtin_amdgcn_rcpf(1.0f + __builtin_amdgcn_exp2f(-1.4426950408889634f * x));
}
__device__ __forceinline__ float fast_tanh(float x) {
    return fmaf(-2.0f, __builtin_amdgcn_rcpf(1.0f + __builtin_amdgcn_exp2f(2.8853900817779268f * x)), 1.0f);
}

// ws: unsigned long long slots[2][1024]. {tag:32 | fp32 bits}. Zero-init:
// buffer0 tag0/val0 == h_0 = 0 (correct); buffer1 receives odd tags.
__global__ void lstm_init_kernel(unsigned long long* ws) {
    int t = threadIdx.x;
    #pragma unroll
    for (int k = 0; k < 8; ++k) ws[t + 256 * k] = 0ull;
}

__global__ __launch_bounds__(TPB, 1) void lstm_persistent_kernel(
    const float* __restrict__ input,   // [4096][64]
    const float* __restrict__ W_ih,    // [4096][64]
    const float* __restrict__ W_hh,    // [4096][1024]
    const float* __restrict__ b_ih,    // [4096]
    const float* __restrict__ b_hh,    // [4096]
    const float* __restrict__ W_lin,   // [1][1024]
    const float* __restrict__ b_lin,   // [1]
    float* __restrict__ out,           // [1]
    unsigned long long* __restrict__ ws)
{
    const int t   = threadIdx.x;
    const int b   = blockIdx.x;
    const int w   = t >> 6;      // wave in block (0..7)
    const int l   = t & 63;      // lane
    const int grp = l >> 4;      // gate q (i,f,g,o)
    const int sl  = l & 15;      // sub-lane within gate group
    const int j   = HPB * b + w; // owned h index
    const int row = grp * HID + j;

    unsigned long long* slot0 = ws;          // even tags
    unsigned long long* slot1 = ws + HID;    // odd tags

    __shared__ float4 wlds4[17 * TPB];       // 136 KB weight staging
    __shared__ float  hs[2][HID];            // double-buffered h (8 KB)
    __shared__ unsigned long long pub[HPB];  // tagged intra-block handoff
    __shared__ float  red[HPB];

    // ---- stage this block's 32 gate-rows into LDS ----
    {
        const float4* Whh4 = (const float4*)(W_hh + (size_t)row * HID);
        #pragma unroll
        for (int c = 0; c < 16; ++c)
            wlds4[c * TPB + t] = Whh4[sl + 16 * c];     // W_hh[row][64c+4sl..+3]
        wlds4[16 * TPB + t] = ((const float4*)(W_ih + (size_t)row * 64))[sl];
    }
    float bias[4];
    #pragma unroll
    for (int q = 0; q < 4; ++q) bias[q] = b_ih[q * HID + j] + b_hh[q * HID + j];
    if (t < HPB) pub[t] = 0ull;
    __syncthreads();   // weights staged, pub initialized

    // ---- LDS -> named registers (NOT remat-able: RA must keep in VGPRs) ----
    const float4 W0  = wlds4[ 0 * TPB + t];
    const float4 W1  = wlds4[ 1 * TPB + t];
    const float4 W2  = wlds4[ 2 * TPB + t];
    const float4 W3  = wlds4[ 3 * TPB + t];
    const float4 W4  = wlds4[ 4 * TPB + t];
    const float4 W5  = wlds4[ 5 * TPB + t];
    const float4 W6  = wlds4[ 6 * TPB + t];
    const float4 W7  = wlds4[ 7 * TPB + t];
    const float4 W8  = wlds4[ 8 * TPB + t];
    const float4 W9  = wlds4[ 9 * TPB + t];
    const float4 W10 = wlds4[10 * TPB + t];
    const float4 W11 = wlds4[11 * TPB + t];
    const float4 W12 = wlds4[12 * TPB + t];
    const float4 W13 = wlds4[13 * TPB + t];
    const float4 W14 = wlds4[14 * TPB + t];
    const float4 W15 = wlds4[15 * TPB + t];
    const float4 W16 = wlds4[16 * TPB + t];   // W_ih fragment

    const float4* xin4 = (const float4*)input;
    float c_state = 0.0f;

    for (int s = 0; s < SEQ_LEN; ++s) {
        float4 x4 = xin4[s * 16 + sl];   // issue before poll (cacheable)

        // ---- depth-2 rotated poll of 2 tagged slots ----
        // Two batches of loads in flight; check batch A while batch B flies
        // (vmcnt(2) waits). Sampling period per address ~ RT/2 instead of RT.
        unsigned long long* rs = (s & 1) ? slot1 : slot0;
        const unsigned tag = (unsigned)s;
        unsigned long long v0, v1;
        {
            unsigned long long a0 = ALD(&rs[t]), a1 = ALD(&rs[t + 512]);
            for (;;) {
                unsigned long long b0 = ALD(&rs[t]), b1 = ALD(&rs[t + 512]);
                if (((unsigned)(a0 >> 32) == tag) & ((unsigned)(a1 >> 32) == tag)) {
                    v0 = a0; v1 = a1; break;
                }
                a0 = ALD(&rs[t]); a1 = ALD(&rs[t + 512]);
                if (((unsigned)(b0 >> 32) == tag) & ((unsigned)(b1 >> 32) == tag)) {
                    v0 = b0; v1 = b1; break;
                }
            }
        }

        float* hsb = hs[s & 1];
        hsb[t      ] = __uint_as_float((unsigned)(v0 & 0xffffffffull));
        hsb[t + 512] = __uint_as_float((unsigned)(v1 & 0xffffffffull));

        __syncthreads();   // the ONE barrier per step: full h_s staged

        // ---- 68 FMAs: weights from REGISTERS, h broadcast-read from LDS ----
        const float4* hs4 = (const float4*)hsb;
        float a0 = 0.f, a1 = 0.f, a2 = 0.f, a3 = 0.f;
        #define FMA_CHUNK(Wc, c, acc) { float4 h4_ = hs4[16 * (c) + sl];      \
            acc = fmaf((Wc).x, h4_.x, acc); acc = fmaf((Wc).y, h4_.y, acc);   \
            acc = fmaf((Wc).z, h4_.z, acc); acc = fmaf((Wc).w, h4_.w, acc); }
        FMA_CHUNK(W0,  0, a0) FMA_CHUNK(W1,  1, a1)
        FMA_CHUNK(W2,  2, a2) FMA_CHUNK(W3,  3, a3)
        FMA_CHUNK(W4,  4, a0) FMA_CHUNK(W5,  5, a1)
        FMA_CHUNK(W6,  6, a2) FMA_CHUNK(W7,  7, a3)
        FMA_CHUNK(W8,  8, a0) FMA_CHUNK(W9,  9, a1)
        FMA_CHUNK(W10, 10, a2) FMA_CHUNK(W11, 11, a3)
        FMA_CHUNK(W12, 12, a0) FMA_CHUNK(W13, 13, a1)
        FMA_CHUNK(W14, 14, a2) FMA_CHUNK(W15, 15, a3)
        #undef FMA_CHUNK
        a0 = fmaf(W16.x, x4.x, a0); a1 = fmaf(W16.y, x4.y, a1);
        a2 = fmaf(W16.z, x4.z, a2); a3 = fmaf(W16.w, x4.w, a3);
        float acc = (a0 + a1) + (a2 + a3);

        // reduce across 16 lanes of the gate group
        acc += __shfl_xor(acc, 1);
        acc += __shfl_xor(acc, 2);
        acc += __shfl_xor(acc, 4);
        acc += __shfl_xor(acc, 8);

        float gi = __shfl(acc, 0)  + bias[0];
        float gf = __shfl(acc, 16) + bias[1];
        float gg = __shfl(acc, 32) + bias[2];
        float go = __shfl(acc, 48) + bias[3];

        float ig = fast_sigmoid(gi);
        float fg = fast_sigmoid(gf);
        float cg = fast_tanh(gg);
        float og = fast_sigmoid(go);
        c_state  = fmaf(fg, c_state, ig * cg);
        float hn = og * fast_tanh(c_state);

        // ---- intra-block handoff: wave w lane 0 posts tagged hn to LDS ----
        const unsigned ntag = (unsigned)(s + 1);
        if (l == 0) {
            unsigned long long pv = ((unsigned long long)ntag << 32) |
                                    (unsigned long long)__float_as_uint(hn);
            __hip_atomic_store(&pub[w], pv, __ATOMIC_RELAXED, __HIP_MEMORY_SCOPE_WORKGROUP);
        }
        // ---- wave 0 lanes 0..7 gather the 8 words, publish one 64B line ----
        if (w == 0 && l < HPB) {
            unsigned long long pv;
            do {
                pv = __hip_atomic_load(&pub[l], __ATOMIC_RELAXED, __HIP_MEMORY_SCOPE_WORKGROUP);
            } while ((unsigned)(pv >> 32) != ntag);
            unsigned long long* wsl = (s & 1) ? slot0 : slot1;   // buffer (s+1)&1
            AST(&wsl[HPB * b + l], pv);
        }
        // no trailing barrier: hs double-buffered; slot-tag deps bound skew
    }

    // ---- final projection: h_4096 (tag 4096, even -> slot0) . W_lin + b_lin ----
    if (b == 0) {
        const unsigned tag = (unsigned)SEQ_LEN;
        unsigned long long v0, v1;
        bool r0 = false, r1 = false;
        do {
            if (!r0) { v0 = ALD(&slot0[t      ]); r0 = ((unsigned)(v0 >> 32) == tag); }
            if (!r1) { v1 = ALD(&slot0[t + 512]); r1 = ((unsigned)(v1 >> 32) == tag); }
        } while (!(r0 && r1));
        float p = __uint_as_float((unsigned)(v0 & 0xffffffffull)) * W_lin[t] +
                  __uint_as_float((unsigned)(v1 & 0xffffffffull)) * W_lin[t + 512];
        #pragma unroll
        for (int m = 32; m >= 1; m >>= 1) p += __shfl_xor(p, m);
        if (l == 0) red[w] = p;
        __syncthreads();
        if (t == 0) {
            float r = 0.f;
            #pragma unroll
            for (int k = 0; k < HPB; ++k) r += red[k];
            out[0] = r + b_lin[0];
        }
    }
}

extern "C" void kernel_launch(void* const* d_in, const int* in_sizes, int n_in,
                              void* d_out, int out_size, void* d_ws, size_t ws_size,
                              hipStream_t stream) {
    const float* input = (const float*)d_in[0];
    const float* W_ih  = (const float*)d_in[1];
    const float* W_hh  = (const float*)d_in[2];
    const float* b_ih  = (const float*)d_in[3];
    const float* b_hh  = (const float*)d_in[4];
    const float* W_lin = (const float*)d_in[5];
    const float* b_lin = (const float*)d_in[6];
    float* out = (float*)d_out;
    unsigned long long* ws = (unsigned long long*)d_ws;

    hipLaunchKernelGGL(lstm_init_kernel, dim3(1), dim3(256), 0, stream, ws);

    void* args[] = { (void*)&input, (void*)&W_ih, (void*)&W_hh, (void*)&b_ih,
                     (void*)&b_hh, (void*)&W_lin, (void*)&b_lin, (void*)&out, (void*)&ws };
    (void)hipLaunchCooperativeKernel((void*)lstm_persistent_kernel, dim3(NBLK), dim3(TPB),
                                     args, 0, stream);
}